// Round 5
// baseline (1249.422 us; speedup 1.0000x reference)
//
#include <hip/hip_runtime.h>
#include <hip/hip_bf16.h>
#include <stdint.h>

#define T_TOK 4096
#define HID   2048
#define FFN_D 4096
#define NE    8
#define BM    128
#define BN    128

typedef __attribute__((ext_vector_type(8))) short  short8;
typedef __attribute__((ext_vector_type(4))) float  f32x4;
typedef __attribute__((ext_vector_type(4))) unsigned short u16x4;
typedef unsigned short u16;

__device__ __forceinline__ u16 f2bf(float f) {
    unsigned u = __float_as_uint(f);
    u += 0x7FFFu + ((u >> 16) & 1u);   // RNE
    return (u16)(u >> 16);
}
__device__ __forceinline__ float bf2f(u16 v) {
    return __uint_as_float(((unsigned)v) << 16);
}

// direct global->LDS, 16B per lane; LDS dest = wave-uniform base + lane*16
#define GLD16(g, l) __builtin_amdgcn_global_load_lds( \
    (const __attribute__((address_space(1))) unsigned int*)(g), \
    (__attribute__((address_space(3))) unsigned int*)(l), 16, 0, 0)

// ---------------- generic fp32 -> bf16 converter (grid-stride, x8 vectorized) ----
__global__ void k_convert(const float* __restrict__ s, u16* __restrict__ d, long n8) {
    for (long i = (long)blockIdx.x * 256 + threadIdx.x; i < n8; i += (long)gridDim.x * 256) {
        f32x4 a = *((const f32x4*)s + i * 2);
        f32x4 b = *((const f32x4*)s + i * 2 + 1);
        short8 o;
#pragma unroll
        for (int q = 0; q < 4; ++q) { o[q] = (short)f2bf(a[q]); o[q + 4] = (short)f2bf(b[q]); }
        *(short8*)(d + i * 8) = o;
    }
}

// ---------------- router (1 wave per token) ----------------
__global__ void k_router(const float* __restrict__ x, const float* __restrict__ wr,
                         int* __restrict__ topk_id, float* __restrict__ topk_w,
                         int* __restrict__ counts) {
    int lane = threadIdx.x & 63;
    int t = blockIdx.x * 4 + (threadIdx.x >> 6);
    const float* xr = x + (size_t)t * HID;
    float acc[8];
#pragma unroll
    for (int e = 0; e < 8; ++e) acc[e] = 0.f;
    for (int h = lane; h < HID; h += 64) {
        float xv = xr[h];
        f32x4 w0 = *(const f32x4*)(wr + h * 8);
        f32x4 w1 = *(const f32x4*)(wr + h * 8 + 4);
#pragma unroll
        for (int q = 0; q < 4; ++q) { acc[q] += xv * w0[q]; acc[4 + q] += xv * w1[q]; }
    }
#pragma unroll
    for (int e = 0; e < 8; ++e) {
        float v = acc[e];
#pragma unroll
        for (int s = 32; s > 0; s >>= 1) v += __shfl_xor(v, s);
        acc[e] = v;
    }
    if (lane == 0) {
        int i0 = 0; float l0 = acc[0];
#pragma unroll
        for (int e = 1; e < 8; ++e) if (acc[e] > l0) { l0 = acc[e]; i0 = e; }
        int i1 = -1; float l1 = -3.4e38f;
#pragma unroll
        for (int e = 0; e < 8; ++e) if (e != i0 && acc[e] > l1) { l1 = acc[e]; i1 = e; }
        float wA = 1.f / (1.f + expf(l1 - l0));   // top-2 softmax renorm, denom cancels
        topk_id[t * 2] = i0;  topk_id[t * 2 + 1] = i1;
        topk_w[t * 2] = wA;   topk_w[t * 2 + 1] = 1.f - wA;
        atomicAdd(&counts[i0], 1);
        atomicAdd(&counts[i1], 1);
    }
}

// ---------------- padded scan + fill ----------------
__global__ void k_scan(const int* __restrict__ counts, int* __restrict__ pad_off,
                       int* __restrict__ perm_tok) {
    __shared__ int sTot;
    if (threadIdx.x == 0) {
        int o = 0;
#pragma unroll
        for (int e = 0; e < 8; ++e) { pad_off[e] = o; o += ((counts[e] + BM - 1) / BM) * BM; }
        pad_off[8] = o; sTot = o;
    }
    __syncthreads();
    int tot = sTot;
    for (int i = threadIdx.x; i < tot; i += 256) perm_tok[i] = 0;  // filler = token 0
}

// ---------------- scatter tokens into expert lists ----------------
__global__ void k_scatter(const int* __restrict__ topk_id, int* __restrict__ cursors,
                          const int* __restrict__ pad_off, int* __restrict__ perm_tok,
                          int* __restrict__ pos_of) {
    int t = blockIdx.x * 256 + threadIdx.x;
    if (t >= T_TOK) return;
#pragma unroll
    for (int k = 0; k < 2; ++k) {
        int e = topk_id[t * 2 + k];
        int p = pad_off[e] + atomicAdd(&cursors[e], 1);
        perm_tok[p] = t;
        pos_of[t * 2 + k] = p;
    }
}

// =========== 3-buffer counted-vmcnt MFMA GEMM (T1+T2+T4+T5) ==================
// A [rows,32-chunked K] bf16 (opt. gathered), B [NTOT,KTOT] bf16/expert,
// C [pad,NTOT] bf16.  BK=32 fixed.
// Pipeline per K-step: wait vmcnt(LPT); s_barrier; sched_barrier;
//   STAGE(t+2 -> slot (t+2)%3); ds_read(tile t); setprio(1) MFMA setprio(0).
// vmcnt waits oldest-first (m135), so own tile-t segments are landed at the
// wait; barrier publishes all waves' segments; slot (t+2)%3 was last read at
// t-1 whose ds_reads complete before the pre-barrier MFMA -> no overwrite race.
template<int KTOT, int NTOT, bool DUAL, bool GATHER>
__global__ __launch_bounds__(256) void k_gemm_p(
    const u16* __restrict__ A,
    const u16* __restrict__ B0all,
    const u16* __restrict__ B1all,
    u16* __restrict__ C,
    const int* __restrict__ perm_tok,
    const int* __restrict__ pad_off)
{
    constexpr int BK   = 32;
    constexpr int NB   = NTOT / BN;        // n-blocks
    constexpr int CPX  = NB / 8;           // n-cols per XCD
    constexpr int TILE = BM * BK;          // 4096 u16 = 8KB per buffer
    constexpr int NK   = KTOT / BK;
    constexpr int SGW  = 2;                // 1KB segments per wave per array

    const int bid = blockIdx.x;
    const int xcd = bid & 7;
    const int i   = bid >> 3;
    const int m0  = (i / CPX) * BM;
    if (m0 >= pad_off[8]) return;
    const int n0  = (xcd * CPX + (i % CPX)) * BN;

    int e = 0;
    while (pad_off[e + 1] <= m0) ++e;

    __shared__ u16 As[3 * TILE];
    __shared__ u16 Bs0[3 * TILE];
    __shared__ u16 Bs1[DUAL ? 3 * TILE : 8];
    __shared__ int tokS[GATHER ? BM : 8];

    const int tid = threadIdx.x;
    if (GATHER) {
        if (tid < BM) tokS[tid] = perm_tok[m0 + tid];
        __syncthreads();
    }

    const u16* B0 = B0all + (size_t)e * NTOT * KTOT;
    const u16* B1 = DUAL ? (B1all + (size_t)e * NTOT * KTOT) : B0all;

    const int w = tid >> 6, l = tid & 63;
    // staging: seg covers 16 rows x 32 elems; lane l -> row l/4, phys chunk
    // (l%4)^f(row) with f(row)=(row>>1)&3  (T2 both-sides swizzle, 16B gran)
    int aOff[SGW], bOff[SGW], dOff[SGW];
#pragma unroll
    for (int s = 0; s < SGW; ++s) {
        int seg = w * SGW + s;
        int row = seg * 16 + (l >> 2);
        int f   = (row >> 1) & 3;
        int sl  = (l & 3) ^ f;              // inverse-swizzled source chunk
        int arow = GATHER ? tokS[row] : (m0 + row);
        aOff[s] = arow * KTOT + sl * 8;
        bOff[s] = (n0 + row) * KTOT + sl * 8;
        dOff[s] = seg * 512;                // wave-uniform LDS base (elements)
    }

    const int wm = (w >> 1) * 64;
    const int wn = (w & 1) * 64;
    const int fr = l & 15;
    const int fk = l >> 4;

    // precomputed swizzled read offsets (BK=32 -> single kk, pc = fk^f const)
    int aRd[4], bRd[4];
#pragma unroll
    for (int ii = 0; ii < 4; ++ii) {
        int rowA = wm + ii * 16 + fr;
        aRd[ii] = rowA * BK + ((fk ^ ((rowA >> 1) & 3)) << 3);
        int rowB = wn + ii * 16 + fr;
        bRd[ii] = rowB * BK + ((fk ^ ((rowB >> 1) & 3)) << 3);
    }

    f32x4 acc0[4][4], acc1[4][4];
    const f32x4 fz = {0.f, 0.f, 0.f, 0.f};
#pragma unroll
    for (int ii = 0; ii < 4; ++ii)
#pragma unroll
        for (int jj = 0; jj < 4; ++jj) { acc0[ii][jj] = fz; acc1[ii][jj] = fz; }

    auto STAGE = [&](int t, int slot) {
        const int k0 = t * BK;
        u16* aB  = As  + slot * TILE;
        u16* b0B = Bs0 + slot * TILE;
        u16* b1B = Bs1 + (DUAL ? slot * TILE : 0);
#pragma unroll
        for (int s = 0; s < SGW; ++s) {
            GLD16(A  + aOff[s] + k0, aB  + dOff[s]);
            GLD16(B0 + bOff[s] + k0, b0B + dOff[s]);
            if (DUAL) GLD16(B1 + bOff[s] + k0, b1B + dOff[s]);
        }
    };

    // prologue: two tiles in flight
    STAGE(0, 0);
    STAGE(1, 1);

    int rd = 0, st = 2;
    for (int ks = 0; ks < NK; ++ks) {
        if (ks + 1 < NK) {
            if (DUAL) asm volatile("s_waitcnt vmcnt(6)" ::: "memory");
            else      asm volatile("s_waitcnt vmcnt(4)" ::: "memory");
        } else {
            asm volatile("s_waitcnt vmcnt(0)" ::: "memory");
        }
        __builtin_amdgcn_s_barrier();
        __builtin_amdgcn_sched_barrier(0);   // nothing crosses the barrier

        if (ks + 2 < NK) STAGE(ks + 2, st);

        const u16* aB  = As  + rd * TILE;
        const u16* b0B = Bs0 + rd * TILE;
        const u16* b1B = Bs1 + (DUAL ? rd * TILE : 0);
        short8 af[4], b0f[4], b1f[4];
#pragma unroll
        for (int ii = 0; ii < 4; ++ii) af[ii]  = *(const short8*)(aB  + aRd[ii]);
#pragma unroll
        for (int jj = 0; jj < 4; ++jj) b0f[jj] = *(const short8*)(b0B + bRd[jj]);
        if (DUAL) {
#pragma unroll
            for (int jj = 0; jj < 4; ++jj) b1f[jj] = *(const short8*)(b1B + bRd[jj]);
        }
        __builtin_amdgcn_s_setprio(1);
#pragma unroll
        for (int ii = 0; ii < 4; ++ii)
#pragma unroll
            for (int jj = 0; jj < 4; ++jj) {
                acc0[ii][jj] = __builtin_amdgcn_mfma_f32_16x16x32_bf16(af[ii], b0f[jj], acc0[ii][jj], 0, 0, 0);
                if (DUAL)
                    acc1[ii][jj] = __builtin_amdgcn_mfma_f32_16x16x32_bf16(af[ii], b1f[jj], acc1[ii][jj], 0, 0, 0);
            }
        __builtin_amdgcn_s_setprio(0);

        rd = (rd == 2) ? 0 : rd + 1;
        st = (st == 2) ? 0 : st + 1;
    }

    // epilogue: C/D layout col=lane&15, row=(lane>>4)*4+reg; DUAL -> SwiGLU fuse
    const int er = (l >> 4) * 4;
    const int ec = l & 15;
#pragma unroll
    for (int ii = 0; ii < 4; ++ii)
#pragma unroll
        for (int jj = 0; jj < 4; ++jj)
#pragma unroll
            for (int r = 0; r < 4; ++r) {
                size_t prow = (size_t)(m0 + wm + ii * 16 + er + r);
                int col = n0 + wn + jj * 16 + ec;
                float v = acc0[ii][jj][r];
                float res;
                if (DUAL) {
                    float g3 = acc1[ii][jj][r];
                    res = v / (1.f + __expf(-v)) * g3;   // silu(g1)*g3
                } else {
                    res = v;
                }
                C[prow * NTOT + col] = f2bf(res);
            }
}

// ---------------- weighted combine ----------------
__global__ void k_combine(const u16* __restrict__ y, const int* __restrict__ pos_of,
                          const float* __restrict__ topk_w, float* __restrict__ out) {
    int idx = blockIdx.x * 256 + threadIdx.x;    // exactly T * (H/4)
    int t  = idx >> 9;
    int c4 = (idx & 511) << 2;
    int p0 = pos_of[t * 2], p1 = pos_of[t * 2 + 1];
    float w0 = topk_w[t * 2], w1 = topk_w[t * 2 + 1];
    u16x4 a = *(const u16x4*)(y + (size_t)p0 * HID + c4);
    u16x4 b = *(const u16x4*)(y + (size_t)p1 * HID + c4);
    f32x4 o;
#pragma unroll
    for (int q = 0; q < 4; ++q) o[q] = w0 * bf2f(a[q]) + w1 * bf2f(b[q]);
    *(f32x4*)(out + (size_t)t * HID + c4) = o;
    if (idx == 0) out[(size_t)T_TOK * HID] = 0.f;   // second output: zeros((1,))
}

__global__ void k_init(int* __restrict__ c) {
    if (threadIdx.x < 16) c[threadIdx.x] = 0;       // counts[8] + cursors[8]
}

// ================= fallback GEMM (fp32 B reg-staged) — only if ws too small ======
template<int KTOT, int NTOT, bool DUAL, bool GATHER>
__global__ __launch_bounds__(256) void k_gemm_fb(
    const u16* __restrict__ A,
    const float* __restrict__ Ball0,
    const float* __restrict__ Ball1,
    u16* __restrict__ C,
    const int* __restrict__ perm_tok,
    const int* __restrict__ pad_off)
{
    const int e    = blockIdx.z;
    const int base = pad_off[e];
    const int ne   = pad_off[e + 1] - base;
    const int m0   = blockIdx.y * BM;
    if (m0 >= ne) return;
    const int n0  = blockIdx.x * BN;
    const int tid = threadIdx.x;
    const int BK = 64;

    __shared__ u16 As[BM * 64];
    __shared__ u16 Bs0[BN * 64];
    __shared__ u16 Bs1[DUAL ? BN * 64 : 8];
    __shared__ int tokS[BM];

    const float* B0 = Ball0 + (size_t)e * NTOT * KTOT;
    const float* B1 = DUAL ? (Ball1 + (size_t)e * NTOT * KTOT) : Ball0;

    if (GATHER) {
        if (tid < BM) tokS[tid] = perm_tok[base + m0 + tid];
        __syncthreads();
    }

    const int sr = tid >> 3;
    const int sc = tid & 7;
    const u16*   aRow[4];
    const float* b0Row[4];
    const float* b1Row[4];
    int dIdx[4];
#pragma unroll
    for (int i = 0; i < 4; ++i) {
        int r = sr + 32 * i;
        if (GATHER) aRow[i] = A + (size_t)tokS[r] * KTOT + sc * 8;
        else        aRow[i] = A + (size_t)(base + m0 + r) * KTOT + sc * 8;
        b0Row[i] = B0 + (size_t)(n0 + r) * KTOT + sc * 8;
        b1Row[i] = B1 + (size_t)(n0 + r) * KTOT + sc * 8;
        dIdx[i] = r * BK + ((sc ^ (sr & 7)) << 3);
    }

    const int lane = tid & 63;
    const int wid  = tid >> 6;
    const int wm   = (wid >> 1) * 64;
    const int wn   = (wid & 1) * 64;
    const int fr   = lane & 15;
    const int fk   = lane >> 4;
    const int x7   = fr & 7;

    f32x4 acc0[4][4], acc1[4][4];
    const f32x4 fz = {0.f, 0.f, 0.f, 0.f};
#pragma unroll
    for (int i = 0; i < 4; ++i)
#pragma unroll
        for (int j = 0; j < 4; ++j) { acc0[i][j] = fz; acc1[i][j] = fz; }

    for (int ks = 0; ks < KTOT / BK; ++ks) {
        short8 av[4], b0s[4], b1s[4];
#pragma unroll
        for (int i = 0; i < 4; ++i) {
            av[i] = *(const short8*)(aRow[i]);  aRow[i] += BK;
            f32x4 f0 = *(const f32x4*)(b0Row[i]);
            f32x4 f1 = *(const f32x4*)(b0Row[i] + 4);  b0Row[i] += BK;
#pragma unroll
            for (int q = 0; q < 4; ++q) { b0s[i][q] = (short)f2bf(f0[q]); b0s[i][q + 4] = (short)f2bf(f1[q]); }
            if (DUAL) {
                f32x4 g0 = *(const f32x4*)(b1Row[i]);
                f32x4 g1 = *(const f32x4*)(b1Row[i] + 4);  b1Row[i] += BK;
#pragma unroll
                for (int q = 0; q < 4; ++q) { b1s[i][q] = (short)f2bf(g0[q]); b1s[i][q + 4] = (short)f2bf(g1[q]); }
            }
        }
        __syncthreads();
#pragma unroll
        for (int i = 0; i < 4; ++i) {
            *(short8*)(&As[dIdx[i]])  = av[i];
            *(short8*)(&Bs0[dIdx[i]]) = b0s[i];
            if (DUAL) *(short8*)(&Bs1[dIdx[i]]) = b1s[i];
        }
        __syncthreads();
#pragma unroll
        for (int kk = 0; kk < 2; ++kk) {
            short8 af[4], b0f[4], b1f[4];
            const int ct = ((kk * 4 + fk) ^ x7) << 3;
#pragma unroll
            for (int i = 0; i < 4; ++i) af[i]  = *(const short8*)(&As[(wm + i * 16 + fr) * BK + ct]);
#pragma unroll
            for (int j = 0; j < 4; ++j) b0f[j] = *(const short8*)(&Bs0[(wn + j * 16 + fr) * BK + ct]);
            if (DUAL) {
#pragma unroll
                for (int j = 0; j < 4; ++j) b1f[j] = *(const short8*)(&Bs1[(wn + j * 16 + fr) * BK + ct]);
            }
#pragma unroll
            for (int i = 0; i < 4; ++i)
#pragma unroll
                for (int j = 0; j < 4; ++j) {
                    acc0[i][j] = __builtin_amdgcn_mfma_f32_16x16x32_bf16(af[i], b0f[j], acc0[i][j], 0, 0, 0);
                    if (DUAL)
                        acc1[i][j] = __builtin_amdgcn_mfma_f32_16x16x32_bf16(af[i], b1f[j], acc1[i][j], 0, 0, 0);
                }
        }
        __syncthreads();
    }

    const int er = (lane >> 4) * 4;
    const int ec = lane & 15;
#pragma unroll
    for (int i = 0; i < 4; ++i)
#pragma unroll
        for (int j = 0; j < 4; ++j)
#pragma unroll
            for (int r = 0; r < 4; ++r) {
                size_t prow = (size_t)(base + m0 + wm + i * 16 + er + r);
                int col = n0 + wn + j * 16 + ec;
                float v = acc0[i][j][r];
                float res;
                if (DUAL) {
                    float g3 = acc1[i][j][r];
                    res = v / (1.f + __expf(-v)) * g3;
                } else {
                    res = v;
                }
                C[prow * NTOT + col] = f2bf(res);
            }
}

extern "C" void kernel_launch(void* const* d_in, const int* in_sizes, int n_in,
                              void* d_out, int out_size, void* d_ws, size_t ws_size,
                              hipStream_t stream) {
    const float* x  = (const float*)d_in[0];
    const float* wr = (const float*)d_in[1];
    const float* w1 = (const float*)d_in[2];
    const float* w2 = (const float*)d_in[3];
    const float* w3 = (const float*)d_in[4];
    float* out = (float*)d_out;
    char* ws = (char*)d_ws;

    const size_t NEED = 398594176ull;

    if (ws_size >= NEED) {
        // ---- main path: bf16 weight cache + 3-buffer counted-vmcnt GEMMs ----
        u16*  xb  = (u16*)(ws);                          // 16,777,216
        u16*  wA  = (u16*)(ws + 16777216);               // 134,217,728 (w1b, later w2b)
        u16*  w3b = (u16*)(ws + 150994944);              // 134,217,728
        u16*  hb  = (u16*)(ws + 285212672);              // 75,497,472  (9216 x 4096)
        u16*  yb  = (u16*)(ws + 360710144);              // 37,748,736  (9216 x 2048)
        int*  perm_tok = (int*)(ws + 398458880);
        int*  pos_of   = (int*)(ws + 398495744);
        int*  topk_id  = (int*)(ws + 398528512);
        float* topk_w  = (float*)(ws + 398561280);
        int*  cnt      = (int*)(ws + 398594048);
        int*  counts   = cnt;
        int*  cursors  = cnt + 8;
        int*  pad_off  = cnt + 16;

        k_init<<<1, 64, 0, stream>>>(cnt);
        k_convert<<<2048, 256, 0, stream>>>(x, xb, (long)T_TOK * HID / 8);
        k_router<<<1024, 256, 0, stream>>>(x, wr, topk_id, topk_w, counts);
        k_scan<<<1, 256, 0, stream>>>(counts, pad_off, perm_tok);
        k_scatter<<<16, 256, 0, stream>>>(topk_id, cursors, pad_off, perm_tok, pos_of);

        const long WN8 = (long)NE * FFN_D * HID / 8;
        k_convert<<<4096, 256, 0, stream>>>(w1, wA, WN8);
        k_convert<<<4096, 256, 0, stream>>>(w3, w3b, WN8);

        // stage 1: h = silu(x@w1^T)*(x@w3^T); dual-B, 3-buf pipeline, XCD-chunked
        k_gemm_p<HID, FFN_D, true, true><<<(FFN_D / BN) * 72, 256, 0, stream>>>(
            xb, wA, w3b, hb, perm_tok, pad_off);

        k_convert<<<4096, 256, 0, stream>>>(w2, wA, WN8);  // reuse w1's slot

        // stage 2: y = h @ w2^T; single-B, 3-buf pipeline, XCD-chunked
        k_gemm_p<FFN_D, HID, false, false><<<(HID / BN) * 72, 256, 0, stream>>>(
            hb, wA, (const u16*)nullptr, yb, perm_tok, pad_off);

        k_combine<<<8192, 256, 0, stream>>>(yb, pos_of, topk_w, out);
    } else {
        // ---- fallback: fp32-weight reg-staged path (~130.2 MB) ----
        u16*  xb       = (u16*)(ws);
        u16*  hbuf     = (u16*)(ws + 16777216);
        u16*  ybuf     = (u16*)(ws + 92274688);
        int*  perm_tok = (int*)(ws + 130023424);
        int*  pos_of   = (int*)(ws + 130060288);
        int*  topk_id  = (int*)(ws + 130093056);
        float* topk_w  = (float*)(ws + 130125824);
        int*  cnt      = (int*)(ws + 130158592);
        int*  counts   = cnt;
        int*  cursors  = cnt + 8;
        int*  pad_off  = cnt + 16;

        k_init<<<1, 64, 0, stream>>>(cnt);
        k_convert<<<2048, 256, 0, stream>>>(x, xb, (long)T_TOK * HID / 8);
        k_router<<<1024, 256, 0, stream>>>(x, wr, topk_id, topk_w, counts);
        k_scan<<<1, 256, 0, stream>>>(counts, pad_off, perm_tok);
        k_scatter<<<16, 256, 0, stream>>>(topk_id, cursors, pad_off, perm_tok, pos_of);

        k_gemm_fb<HID, FFN_D, true, true><<<dim3(FFN_D / BN, 32, NE), 256, 0, stream>>>(
            xb, w1, w3, hbuf, perm_tok, pad_off);
        k_gemm_fb<FFN_D, HID, false, false><<<dim3(HID / BN, 32, NE), 256, 0, stream>>>(
            hbuf, w2, (const float*)nullptr, ybuf, perm_tok, pad_off);

        k_combine<<<8192, 256, 0, stream>>>(ybuf, pos_of, topk_w, out);
    }
}

// Round 6
// 895.149 us; speedup vs baseline: 1.3958x; 1.3958x over previous
//
#include <hip/hip_runtime.h>
#include <hip/hip_bf16.h>
#include <stdint.h>

#define T_TOK 4096
#define HID   2048
#define FFN_D 4096
#define NE    8
#define PADB  256     // expert padding granularity = BM of the 8-wave GEMM

typedef __attribute__((ext_vector_type(8))) short  short8;
typedef __attribute__((ext_vector_type(4))) float  f32x4;
typedef __attribute__((ext_vector_type(4))) unsigned short u16x4;
typedef unsigned short u16;

__device__ __forceinline__ u16 f2bf(float f) {
    unsigned u = __float_as_uint(f);
    u += 0x7FFFu + ((u >> 16) & 1u);   // RNE
    return (u16)(u >> 16);
}
__device__ __forceinline__ float bf2f(u16 v) {
    return __uint_as_float(((unsigned)v) << 16);
}

// direct global->LDS, 16B per lane; LDS dest = wave-uniform base + lane*16
#define GLD16(g, l) __builtin_amdgcn_global_load_lds( \
    (const __attribute__((address_space(1))) unsigned int*)(g), \
    (__attribute__((address_space(3))) unsigned int*)(l), 16, 0, 0)

// ---------------- generic fp32 -> bf16 converter ----------------
__global__ void k_convert(const float* __restrict__ s, u16* __restrict__ d, long n8) {
    for (long i = (long)blockIdx.x * 256 + threadIdx.x; i < n8; i += (long)gridDim.x * 256) {
        f32x4 a = *((const f32x4*)s + i * 2);
        f32x4 b = *((const f32x4*)s + i * 2 + 1);
        short8 o;
#pragma unroll
        for (int q = 0; q < 4; ++q) { o[q] = (short)f2bf(a[q]); o[q + 4] = (short)f2bf(b[q]); }
        *(short8*)(d + i * 8) = o;
    }
}

// ---------------- router (1 wave per token) ----------------
__global__ void k_router(const float* __restrict__ x, const float* __restrict__ wr,
                         int* __restrict__ topk_id, float* __restrict__ topk_w,
                         int* __restrict__ counts) {
    int lane = threadIdx.x & 63;
    int t = blockIdx.x * 4 + (threadIdx.x >> 6);
    const float* xr = x + (size_t)t * HID;
    float acc[8];
#pragma unroll
    for (int e = 0; e < 8; ++e) acc[e] = 0.f;
    for (int h = lane; h < HID; h += 64) {
        float xv = xr[h];
        f32x4 w0 = *(const f32x4*)(wr + h * 8);
        f32x4 w1 = *(const f32x4*)(wr + h * 8 + 4);
#pragma unroll
        for (int q = 0; q < 4; ++q) { acc[q] += xv * w0[q]; acc[4 + q] += xv * w1[q]; }
    }
#pragma unroll
    for (int e = 0; e < 8; ++e) {
        float v = acc[e];
#pragma unroll
        for (int s = 32; s > 0; s >>= 1) v += __shfl_xor(v, s);
        acc[e] = v;
    }
    if (lane == 0) {
        int i0 = 0; float l0 = acc[0];
#pragma unroll
        for (int e = 1; e < 8; ++e) if (acc[e] > l0) { l0 = acc[e]; i0 = e; }
        int i1 = -1; float l1 = -3.4e38f;
#pragma unroll
        for (int e = 0; e < 8; ++e) if (e != i0 && acc[e] > l1) { l1 = acc[e]; i1 = e; }
        float wA = 1.f / (1.f + expf(l1 - l0));   // top-2 softmax renorm, denom cancels
        topk_id[t * 2] = i0;  topk_id[t * 2 + 1] = i1;
        topk_w[t * 2] = wA;   topk_w[t * 2 + 1] = 1.f - wA;
        atomicAdd(&counts[i0], 1);
        atomicAdd(&counts[i1], 1);
    }
}

// ---------------- padded scan + fill (pad to 256) ----------------
__global__ void k_scan(const int* __restrict__ counts, int* __restrict__ pad_off,
                       int* __restrict__ perm_tok) {
    __shared__ int sTot;
    if (threadIdx.x == 0) {
        int o = 0;
#pragma unroll
        for (int e = 0; e < 8; ++e) { pad_off[e] = o; o += ((counts[e] + PADB - 1) / PADB) * PADB; }
        pad_off[8] = o; sTot = o;
    }
    __syncthreads();
    int tot = sTot;
    for (int i = threadIdx.x; i < tot; i += 256) perm_tok[i] = 0;  // filler = token 0
}

// ---------------- scatter tokens into expert lists ----------------
__global__ void k_scatter(const int* __restrict__ topk_id, int* __restrict__ cursors,
                          const int* __restrict__ pad_off, int* __restrict__ perm_tok,
                          int* __restrict__ pos_of) {
    int t = blockIdx.x * 256 + threadIdx.x;
    if (t >= T_TOK) return;
#pragma unroll
    for (int k = 0; k < 2; ++k) {
        int e = topk_id[t * 2 + k];
        int p = pad_off[e] + atomicAdd(&cursors[e], 1);
        perm_tok[p] = t;
        pos_of[t * 2 + k] = p;
    }
}

// =========== 256-row 8-wave 4-phase GEMM, wave-owned stage units ============
// BM=256, BK=64, 512 thr (waves 2M x 4N). DUAL: BN=128 (B0=w1,B1=w3, SwiGLU
// fused); single: BN=256. LDS 128KB (2 dbuf). Wave w owns stage unit w (64
// rows of A or B); it issues its 8 global_load_lds for tile t+1 at phases 0-1
// of tile t, so the single vmcnt(0)+barrier at tile end waits on ~600-cycle-old
// loads (covered). 64 MFMA per wave per barrier. Full 3-bit row-XOR swizzle:
// phys chunk = logical ^ (row&7); stage source pre-swizzled (rule 21), so
// ds_read_b128 spans all 32 banks (8-clk floor, conflict-free).
template<int KTOT, int NTOT, bool DUAL, bool GATHER>
__global__ __launch_bounds__(512, 2) void k_gemm8(
    const u16* __restrict__ A,
    const u16* __restrict__ B0all,
    const u16* __restrict__ B1all,
    u16* __restrict__ C,
    const int* __restrict__ perm_tok,
    const int* __restrict__ pad_off)
{
    constexpr int BMt   = 256;
    constexpr int BNt   = DUAL ? 128 : 256;
    constexpr int NI    = DUAL ? 2 : 4;
    constexpr int NB    = NTOT / BNt;
    constexpr int CPX   = NB / 8;
    constexpr int NK    = KTOT / 64;
    constexpr int ATILE = BMt * 64;
    constexpr int BTILE = BNt * 64;
    constexpr int WCW   = DUAL ? 32 : 64;    // wave col width

    const int bid = blockIdx.x;
    const int xcd = bid & 7;
    const int idx = bid >> 3;
    const int m0  = (idx / CPX) * BMt;
    if (m0 >= pad_off[8]) return;
    const int n0  = (xcd * CPX + (idx % CPX)) * BNt;
    int e = 0;
    while (pad_off[e + 1] <= m0) ++e;

    __shared__ u16 As[2 * ATILE];
    __shared__ u16 Bs0[2 * BTILE];
    __shared__ u16 Bs1[DUAL ? 2 * BTILE : 8];
    __shared__ int tokS[GATHER ? BMt : 8];

    const int tid = threadIdx.x;
    const int w = tid >> 6, l = tid & 63;
    if (GATHER) {
        for (int i = tid; i < BMt; i += 512) tokS[i] = perm_tok[m0 + i];
        __syncthreads();
    }

    const u16* B0 = B0all + (size_t)e * NTOT * KTOT;
    const u16* B1 = DUAL ? (B1all + (size_t)e * NTOT * KTOT) : B0all;

    // ---- wave-owned stage unit (8 GLD16/thread/tile) ----
    const u16* gsrc[8];
    u16* ldst[8];
    int tstep;
    {
        const int c = (l & 7) ^ (l >> 3);   // inverse-swizzled source chunk
#pragma unroll
        for (int j = 0; j < 8; ++j) {
            const int rl = j * 8 + (l >> 3);
            if (w < 4) {                                 // A rows w*64..+63
                const int rt = w * 64 + rl;
                const long grow = GATHER ? (long)tokS[rt] : (long)(m0 + rt);
                gsrc[j] = A + grow * KTOT + c * 8;
                ldst[j] = (u16*)As + (w * 64 + j * 8) * 64;
                tstep = ATILE;
            } else if (!DUAL || w < 6) {                 // B0 strip
                const int rt = (DUAL ? ((w - 4) & 1) : (w - 4)) * 64 + rl;
                gsrc[j] = B0 + (size_t)(n0 + rt) * KTOT + c * 8;
                ldst[j] = (u16*)Bs0 + (rt - rl + j * 8) * 64;
                tstep = BTILE;
            } else {                                     // B1 strip (DUAL)
                const int rt = ((w - 4) & 1) * 64 + rl;
                gsrc[j] = B1 + (size_t)(n0 + rt) * KTOT + c * 8;
                ldst[j] = (u16*)Bs1 + (rt - rl + j * 8) * 64;
                tstep = BTILE;
            }
        }
    }

    const int wr = w >> 2, wc = w & 3;
    const int fr = l & 15, fk = l >> 4, x7 = l & 7;
    const int pc0 = ((fk ^ x7) << 3);
    const int pc1 = pc0 ^ 32;                 // (fk+4)^x7 chunk = pc0 XOR 4
    const int aB = (wr * 128 + fr) * 64;
    const int bB = (wc * WCW + fr) * 64;

    f32x4 acc0[8][NI], acc1[8][NI];
    const f32x4 fz = {0.f, 0.f, 0.f, 0.f};
#pragma unroll
    for (int mi = 0; mi < 8; ++mi)
#pragma unroll
        for (int ni = 0; ni < NI; ++ni) { acc0[mi][ni] = fz; if (DUAL) acc1[mi][ni] = fz; }

    // prologue: stage tile 0 into buffer 0, full drain (one-time)
#pragma unroll
    for (int j = 0; j < 8; ++j) GLD16(gsrc[j], ldst[j]);
    asm volatile("s_waitcnt vmcnt(0)" ::: "memory");
    __builtin_amdgcn_s_barrier();
    __builtin_amdgcn_sched_barrier(0);

#pragma unroll 1
    for (int t = 0; t < NK; ++t) {
        const int cb = t & 1, nb2 = cb ^ 1;
        const u16* aC  = (const u16*)As  + cb * ATILE;
        const u16* b0C = (const u16*)Bs0 + cb * BTILE;
        const u16* b1C = (const u16*)Bs1 + (DUAL ? cb * BTILE : 0);
        const long kE = (long)(t + 1) * 64;
        const bool hasNext = (t + 1 < NK);

        short8 af[4], b0f[NI], b1f[NI];

        // ---- P0: stage first half of next tile; mi0-3 x kk0 ----
        if (hasNext) {
#pragma unroll
            for (int j = 0; j < 4; ++j) GLD16(gsrc[j] + kE, ldst[j] + nb2 * tstep);
        }
#pragma unroll
        for (int mi = 0; mi < 4; ++mi) af[mi] = *(const short8*)(aC + aB + mi * 1024 + pc0);
#pragma unroll
        for (int ni = 0; ni < NI; ++ni) {
            b0f[ni] = *(const short8*)(b0C + bB + ni * 1024 + pc0);
            if (DUAL) b1f[ni] = *(const short8*)(b1C + bB + ni * 1024 + pc0);
        }
        __builtin_amdgcn_s_setprio(1);
#pragma unroll
        for (int mi = 0; mi < 4; ++mi)
#pragma unroll
            for (int ni = 0; ni < NI; ++ni) {
                acc0[mi][ni] = __builtin_amdgcn_mfma_f32_16x16x32_bf16(af[mi], b0f[ni], acc0[mi][ni], 0, 0, 0);
                if (DUAL)
                    acc1[mi][ni] = __builtin_amdgcn_mfma_f32_16x16x32_bf16(af[mi], b1f[ni], acc1[mi][ni], 0, 0, 0);
            }
        __builtin_amdgcn_s_setprio(0);

        // ---- P1: stage second half; mi4-7 x kk0 ----
        if (hasNext) {
#pragma unroll
            for (int j = 4; j < 8; ++j) GLD16(gsrc[j] + kE, ldst[j] + nb2 * tstep);
        }
#pragma unroll
        for (int mi = 0; mi < 4; ++mi) af[mi] = *(const short8*)(aC + aB + (mi + 4) * 1024 + pc0);
        __builtin_amdgcn_s_setprio(1);
#pragma unroll
        for (int mi = 0; mi < 4; ++mi)
#pragma unroll
            for (int ni = 0; ni < NI; ++ni) {
                acc0[mi + 4][ni] = __builtin_amdgcn_mfma_f32_16x16x32_bf16(af[mi], b0f[ni], acc0[mi + 4][ni], 0, 0, 0);
                if (DUAL)
                    acc1[mi + 4][ni] = __builtin_amdgcn_mfma_f32_16x16x32_bf16(af[mi], b1f[ni], acc1[mi + 4][ni], 0, 0, 0);
            }
        __builtin_amdgcn_s_setprio(0);

        // ---- P2: mi0-3 x kk1 ----
#pragma unroll
        for (int mi = 0; mi < 4; ++mi) af[mi] = *(const short8*)(aC + aB + mi * 1024 + pc1);
#pragma unroll
        for (int ni = 0; ni < NI; ++ni) {
            b0f[ni] = *(const short8*)(b0C + bB + ni * 1024 + pc1);
            if (DUAL) b1f[ni] = *(const short8*)(b1C + bB + ni * 1024 + pc1);
        }
        __builtin_amdgcn_s_setprio(1);
#pragma unroll
        for (int mi = 0; mi < 4; ++mi)
#pragma unroll
            for (int ni = 0; ni < NI; ++ni) {
                acc0[mi][ni] = __builtin_amdgcn_mfma_f32_16x16x32_bf16(af[mi], b0f[ni], acc0[mi][ni], 0, 0, 0);
                if (DUAL)
                    acc1[mi][ni] = __builtin_amdgcn_mfma_f32_16x16x32_bf16(af[mi], b1f[ni], acc1[mi][ni], 0, 0, 0);
            }
        __builtin_amdgcn_s_setprio(0);

        // ---- P3: mi4-7 x kk1 ----
#pragma unroll
        for (int mi = 0; mi < 4; ++mi) af[mi] = *(const short8*)(aC + aB + (mi + 4) * 1024 + pc1);
        __builtin_amdgcn_s_setprio(1);
#pragma unroll
        for (int mi = 0; mi < 4; ++mi)
#pragma unroll
            for (int ni = 0; ni < NI; ++ni) {
                acc0[mi + 4][ni] = __builtin_amdgcn_mfma_f32_16x16x32_bf16(af[mi], b0f[ni], acc0[mi + 4][ni], 0, 0, 0);
                if (DUAL)
                    acc1[mi + 4][ni] = __builtin_amdgcn_mfma_f32_16x16x32_bf16(af[mi], b1f[ni], acc1[mi + 4][ni], 0, 0, 0);
            }
        __builtin_amdgcn_s_setprio(0);

        // ---- tile boundary: own stages (issued at P0/P1) landed; publish ----
        asm volatile("s_waitcnt vmcnt(0)" ::: "memory");
        __builtin_amdgcn_s_barrier();
        __builtin_amdgcn_sched_barrier(0);
    }

    // epilogue: C/D layout col=lane&15, row=(lane>>4)*4+reg; DUAL -> SwiGLU
    const int er = (l >> 4) * 4;
    const int ec = l & 15;
#pragma unroll
    for (int mi = 0; mi < 8; ++mi)
#pragma unroll
        for (int ni = 0; ni < NI; ++ni)
#pragma unroll
            for (int r = 0; r < 4; ++r) {
                size_t prow = (size_t)(m0 + wr * 128 + mi * 16 + er + r);
                int col = n0 + wc * WCW + ni * 16 + ec;
                float v = acc0[mi][ni][r];
                float res;
                if (DUAL) {
                    float g3 = acc1[mi][ni][r];
                    res = v / (1.f + __expf(-v)) * g3;   // silu(g1)*g3
                } else {
                    res = v;
                }
                C[prow * NTOT + col] = f2bf(res);
            }
}

// ---------------- weighted combine ----------------
__global__ void k_combine(const u16* __restrict__ y, const int* __restrict__ pos_of,
                          const float* __restrict__ topk_w, float* __restrict__ out) {
    int idx = blockIdx.x * 256 + threadIdx.x;    // exactly T * (H/4)
    int t  = idx >> 9;
    int c4 = (idx & 511) << 2;
    int p0 = pos_of[t * 2], p1 = pos_of[t * 2 + 1];
    float w0 = topk_w[t * 2], w1 = topk_w[t * 2 + 1];
    u16x4 a = *(const u16x4*)(y + (size_t)p0 * HID + c4);
    u16x4 b = *(const u16x4*)(y + (size_t)p1 * HID + c4);
    f32x4 o;
#pragma unroll
    for (int q = 0; q < 4; ++q) o[q] = w0 * bf2f(a[q]) + w1 * bf2f(b[q]);
    *(f32x4*)(out + (size_t)t * HID + c4) = o;
    if (idx == 0) out[(size_t)T_TOK * HID] = 0.f;   // second output: zeros((1,))
}

__global__ void k_init(int* __restrict__ c) {
    if (threadIdx.x < 16) c[threadIdx.x] = 0;       // counts[8] + cursors[8]
}

// ================= fallback GEMM (fp32 B reg-staged) — only if ws too small ======
template<int KTOT, int NTOT, bool DUAL, bool GATHER>
__global__ __launch_bounds__(256) void k_gemm_fb(
    const u16* __restrict__ A,
    const float* __restrict__ Ball0,
    const float* __restrict__ Ball1,
    u16* __restrict__ C,
    const int* __restrict__ perm_tok,
    const int* __restrict__ pad_off)
{
    const int BMf = 128;
    const int e    = blockIdx.z;
    const int base = pad_off[e];
    const int ne   = pad_off[e + 1] - base;
    const int m0   = blockIdx.y * BMf;
    if (m0 >= ne) return;
    const int n0  = blockIdx.x * 128;
    const int tid = threadIdx.x;
    const int BK = 64;

    __shared__ u16 As[128 * 64];
    __shared__ u16 Bs0[128 * 64];
    __shared__ u16 Bs1[DUAL ? 128 * 64 : 8];
    __shared__ int tokS[128];

    const float* B0 = Ball0 + (size_t)e * NTOT * KTOT;
    const float* B1 = DUAL ? (Ball1 + (size_t)e * NTOT * KTOT) : Ball0;

    if (GATHER) {
        if (tid < 128) tokS[tid] = perm_tok[base + m0 + tid];
        __syncthreads();
    }

    const int sr = tid >> 3;
    const int sc = tid & 7;
    const u16*   aRow[4];
    const float* b0Row[4];
    const float* b1Row[4];
    int dIdx[4];
#pragma unroll
    for (int i = 0; i < 4; ++i) {
        int r = sr + 32 * i;
        if (GATHER) aRow[i] = A + (size_t)tokS[r] * KTOT + sc * 8;
        else        aRow[i] = A + (size_t)(base + m0 + r) * KTOT + sc * 8;
        b0Row[i] = B0 + (size_t)(n0 + r) * KTOT + sc * 8;
        b1Row[i] = B1 + (size_t)(n0 + r) * KTOT + sc * 8;
        dIdx[i] = r * BK + ((sc ^ (sr & 7)) << 3);
    }

    const int lane = tid & 63;
    const int wid  = tid >> 6;
    const int wm   = (wid >> 1) * 64;
    const int wn   = (wid & 1) * 64;
    const int fr   = lane & 15;
    const int fk   = lane >> 4;
    const int x7   = fr & 7;

    f32x4 acc0[4][4], acc1[4][4];
    const f32x4 fz = {0.f, 0.f, 0.f, 0.f};
#pragma unroll
    for (int i = 0; i < 4; ++i)
#pragma unroll
        for (int j = 0; j < 4; ++j) { acc0[i][j] = fz; acc1[i][j] = fz; }

    for (int ks = 0; ks < KTOT / BK; ++ks) {
        short8 av[4], b0s[4], b1s[4];
#pragma unroll
        for (int i = 0; i < 4; ++i) {
            av[i] = *(const short8*)(aRow[i]);  aRow[i] += BK;
            f32x4 f0 = *(const f32x4*)(b0Row[i]);
            f32x4 f1 = *(const f32x4*)(b0Row[i] + 4);  b0Row[i] += BK;
#pragma unroll
            for (int q = 0; q < 4; ++q) { b0s[i][q] = (short)f2bf(f0[q]); b0s[i][q + 4] = (short)f2bf(f1[q]); }
            if (DUAL) {
                f32x4 g0 = *(const f32x4*)(b1Row[i]);
                f32x4 g1 = *(const f32x4*)(b1Row[i] + 4);  b1Row[i] += BK;
#pragma unroll
                for (int q = 0; q < 4; ++q) { b1s[i][q] = (short)f2bf(g0[q]); b1s[i][q + 4] = (short)f2bf(g1[q]); }
            }
        }
        __syncthreads();
#pragma unroll
        for (int i = 0; i < 4; ++i) {
            *(short8*)(&As[dIdx[i]])  = av[i];
            *(short8*)(&Bs0[dIdx[i]]) = b0s[i];
            if (DUAL) *(short8*)(&Bs1[dIdx[i]]) = b1s[i];
        }
        __syncthreads();
#pragma unroll
        for (int kk = 0; kk < 2; ++kk) {
            short8 af[4], b0f[4], b1f[4];
            const int ct = ((kk * 4 + fk) ^ x7) << 3;
#pragma unroll
            for (int i = 0; i < 4; ++i) af[i]  = *(const short8*)(&As[(wm + i * 16 + fr) * BK + ct]);
#pragma unroll
            for (int j = 0; j < 4; ++j) b0f[j] = *(const short8*)(&Bs0[(wn + j * 16 + fr) * BK + ct]);
            if (DUAL) {
#pragma unroll
                for (int j = 0; j < 4; ++j) b1f[j] = *(const short8*)(&Bs1[(wn + j * 16 + fr) * BK + ct]);
            }
#pragma unroll
            for (int i = 0; i < 4; ++i)
#pragma unroll
                for (int j = 0; j < 4; ++j) {
                    acc0[i][j] = __builtin_amdgcn_mfma_f32_16x16x32_bf16(af[i], b0f[j], acc0[i][j], 0, 0, 0);
                    if (DUAL)
                        acc1[i][j] = __builtin_amdgcn_mfma_f32_16x16x32_bf16(af[i], b1f[j], acc1[i][j], 0, 0, 0);
                }
        }
        __syncthreads();
    }

    const int er = (lane >> 4) * 4;
    const int ec = lane & 15;
#pragma unroll
    for (int i = 0; i < 4; ++i)
#pragma unroll
        for (int j = 0; j < 4; ++j)
#pragma unroll
            for (int r = 0; r < 4; ++r) {
                size_t prow = (size_t)(base + m0 + wm + i * 16 + er + r);
                int col = n0 + wn + j * 16 + ec;
                float v = acc0[i][j][r];
                float res;
                if (DUAL) {
                    float g3 = acc1[i][j][r];
                    res = v / (1.f + __expf(-v)) * g3;
                } else {
                    res = v;
                }
                C[prow * NTOT + col] = f2bf(res);
            }
}

extern "C" void kernel_launch(void* const* d_in, const int* in_sizes, int n_in,
                              void* d_out, int out_size, void* d_ws, size_t ws_size,
                              hipStream_t stream) {
    const float* x  = (const float*)d_in[0];
    const float* wr = (const float*)d_in[1];
    const float* w1 = (const float*)d_in[2];
    const float* w2 = (const float*)d_in[3];
    const float* w3 = (const float*)d_in[4];
    float* out = (float*)d_out;
    char* ws = (char*)d_ws;

    const size_t NEED = 369240064ull;

    if (ws_size >= NEED) {
        // ---- main path ----
        u16*  xb  = (u16*)(ws);                          // 16,777,216
        u16*  wA  = (u16*)(ws + 16777216);               // 134,217,728 (w1b, later w2b)
        u16*  w3b = (u16*)(ws + 150994944);              // 134,217,728 (w3b; later aliased by yb)
        u16*  hb  = (u16*)(ws + 285212672);              // 83,886,080  (10240 x 4096 bf16)
        u16*  yb  = (u16*)(ws + 150994944);              // 41,943,040  alias over w3b (free after gemm1)
        int*  perm_tok = (int*)(ws + 369098752);         // 10240 ints
        int*  pos_of   = (int*)(ws + 369139712);
        int*  topk_id  = (int*)(ws + 369172480);
        float* topk_w  = (float*)(ws + 369205248);
        int*  cnt      = (int*)(ws + 369238016);
        int*  counts   = cnt;
        int*  cursors  = cnt + 8;
        int*  pad_off  = cnt + 16;

        k_init<<<1, 64, 0, stream>>>(cnt);
        k_convert<<<2048, 256, 0, stream>>>(x, xb, (long)T_TOK * HID / 8);
        k_router<<<1024, 256, 0, stream>>>(x, wr, topk_id, topk_w, counts);
        k_scan<<<1, 256, 0, stream>>>(counts, pad_off, perm_tok);
        k_scatter<<<16, 256, 0, stream>>>(topk_id, cursors, pad_off, perm_tok, pos_of);

        const long WN8 = (long)NE * FFN_D * HID / 8;
        k_convert<<<4096, 256, 0, stream>>>(w1, wA, WN8);
        k_convert<<<4096, 256, 0, stream>>>(w3, w3b, WN8);

        // stage 1: h = silu(x@w1^T)*(x@w3^T); dual-B BN=128, 40 m-blocks cap
        k_gemm8<HID, FFN_D, true, true><<<(FFN_D / 128) * 40, 512, 0, stream>>>(
            xb, wA, w3b, hb, perm_tok, pad_off);

        k_convert<<<4096, 256, 0, stream>>>(w2, wA, WN8);  // reuse w1's slot

        // stage 2: y = h @ w2^T; single-B BN=256 (yb aliases w3b region)
        k_gemm8<FFN_D, HID, false, false><<<(HID / 256) * 40, 512, 0, stream>>>(
            hb, wA, (const u16*)nullptr, yb, perm_tok, pad_off);

        k_combine<<<8192, 256, 0, stream>>>(yb, pos_of, topk_w, out);
    } else {
        // ---- fallback: fp32-weight reg-staged path (~130.4 MB) ----
        u16*  xb       = (u16*)(ws);
        u16*  hbuf     = (u16*)(ws + 16777216);          // 10240 x 4096 would overflow; pad<=10232 fits 128-pad too
        u16*  ybuf     = (u16*)(ws + 16777216 + 83886080);
        int*  perm_tok = (int*)(ws + 16777216 + 83886080 + 41943040);
        int*  pos_of   = perm_tok + 10240;
        int*  topk_id  = pos_of + 8192;
        float* topk_w  = (float*)(topk_id + 8192);
        int*  cnt      = (int*)(topk_w + 8192);
        int*  counts   = cnt;
        int*  cursors  = cnt + 8;
        int*  pad_off  = cnt + 16;

        k_init<<<1, 64, 0, stream>>>(cnt);
        k_convert<<<2048, 256, 0, stream>>>(x, xb, (long)T_TOK * HID / 8);
        k_router<<<1024, 256, 0, stream>>>(x, wr, topk_id, topk_w, counts);
        k_scan<<<1, 256, 0, stream>>>(counts, pad_off, perm_tok);
        k_scatter<<<16, 256, 0, stream>>>(topk_id, cursors, pad_off, perm_tok, pos_of);

        k_gemm_fb<HID, FFN_D, true, true><<<dim3(FFN_D / 128, 34, NE), 256, 0, stream>>>(
            xb, w1, w3, hbuf, perm_tok, pad_off);
        k_gemm_fb<FFN_D, HID, false, false><<<dim3(HID / 128, 34, NE), 256, 0, stream>>>(
            hbuf, w2, (const float*)nullptr, ybuf, perm_tok, pad_off);

        k_combine<<<8192, 256, 0, stream>>>(ybuf, pos_of, topk_w, out);
    }
}